// Round 2
// baseline (4249.161 us; speedup 1.0000x reference)
//
#include <hip/hip_runtime.h>
#include <hip/hip_bf16.h>

#define NN 50000
#define EE 400000
#define EPSF 1e-5f

typedef unsigned short u16;
__device__ __forceinline__ float b2f(u16 u) { return __uint_as_float(((unsigned)u) << 16); }
__device__ __forceinline__ u16 f2b(float f) {
  unsigned x = __float_as_uint(f);
  unsigned r = x + 0x7FFFu + ((x >> 16) & 1u);   // RNE
  return (u16)(r >> 16);
}
__device__ __forceinline__ unsigned pack2(float lo, float hi) {
  return (unsigned)f2b(lo) | ((unsigned)f2b(hi) << 16);
}

// ---------------------------------------------------------------- conv_in
// x0[n,c,t] = sum_ci X[n,ci,t]*W[c,ci] + b[c]   (N,16,8)fp32 -> (N,32,8)bf16
__global__ __launch_bounds__(256) void k_convin(
    const float* __restrict__ X, u16* __restrict__ out,
    const float* __restrict__ Wi, const float* __restrict__ bi)
{
  __shared__ float xs[1024];      // 8 nodes x 128
  __shared__ float wi[16 * 33];   // [ci][co] padded
  const int tid = threadIdx.x;
  for (int idx = tid; idx < 512; idx += 256) {
    int co = idx >> 4, ci = idx & 15;
    wi[ci * 33 + co] = Wi[idx];
  }
  const long xbase = (long)blockIdx.x * 1024;
  ((float4*)xs)[tid] = ((const float4*)(X + xbase))[tid];
  __syncthreads();
  const int nl = tid >> 5, c = tid & 31;
  float acc[8];
  {
    float bc = bi[c];
#pragma unroll
    for (int t = 0; t < 8; ++t) acc[t] = bc;
  }
  const float* xrow = xs + (nl << 7);
  for (int ci = 0; ci < 16; ++ci) {
    float w = wi[ci * 33 + c];
    float4 xa = *(const float4*)(xrow + ci * 8);
    float4 xb = *(const float4*)(xrow + ci * 8 + 4);
    acc[0] += xa.x * w; acc[1] += xa.y * w; acc[2] += xa.z * w; acc[3] += xa.w * w;
    acc[4] += xb.x * w; acc[5] += xb.y * w; acc[6] += xb.z * w; acc[7] += xb.w * w;
  }
  uint4 o;
  o.x = pack2(acc[0], acc[1]); o.y = pack2(acc[2], acc[3]);
  o.z = pack2(acc[4], acc[5]); o.w = pack2(acc[6], acc[7]);
  *(uint4*)(out + (long)blockIdx.x * 2048 + tid * 8) = o;
}

// ---------------------------------------------------------------- degree
__global__ void k_deg(const int* __restrict__ dst, int* __restrict__ degi)
{
  int e = blockIdx.x * 256 + threadIdx.x;
  if (e < EE) atomicAdd(degi + dst[e], 1);
}
__global__ void k_dinv(const int* __restrict__ degi, float* __restrict__ dinv)
{
  int n = blockIdx.x * 256 + threadIdx.x;
  if (n < NN) dinv[n] = rsqrtf((float)degi[n] + 1.0f);
}

// ---------------------------------------------------------------- gated conv
// out(bf16) = relu(P * sigmoid(Q) + R); k=3 pad=1 over t; per-channel stats.
#define CONV_STEP(ACC, W0, W1, W2)                    \
  ACC[0] += xv[0]*W1 + xv[1]*W2;                      \
  ACC[1] += xv[0]*W0 + xv[1]*W1 + xv[2]*W2;           \
  ACC[2] += xv[1]*W0 + xv[2]*W1 + xv[3]*W2;           \
  ACC[3] += xv[2]*W0 + xv[3]*W1 + xv[4]*W2;           \
  ACC[4] += xv[3]*W0 + xv[4]*W1 + xv[5]*W2;           \
  ACC[5] += xv[4]*W0 + xv[5]*W1 + xv[6]*W2;           \
  ACC[6] += xv[5]*W0 + xv[6]*W1 + xv[7]*W2;           \
  ACC[7] += xv[6]*W0 + xv[7]*W1;

template<int INBF>
__global__ __launch_bounds__(256) void k_gated(
    const void* __restrict__ in_, u16* __restrict__ out,
    const float* __restrict__ Wg,   // (3,32,32,3)
    const float* __restrict__ bg,   // (3,32)
    const float* __restrict__ aff, const float* __restrict__ bff, // per-f (256) or null
    float* __restrict__ s1, float* __restrict__ s2)               // [32]
{
  __shared__ float xs[2048];
  __shared__ float wl[3 * 96 * 33];
  __shared__ float red1[128], red2[128];
  const int tid = threadIdx.x;

  for (int idx = tid; idx < 9216; idx += 256) {
    int conv = idx / 3072;
    int r = idx - conv * 3072;
    int co = r / 96;
    int r2 = r - co * 96;                 // ci*3+dt
    wl[conv * 3168 + r2 * 33 + co] = Wg[idx];
  }
  const long base = (long)blockIdx.x * 2048;
  if (INBF) {
    const uint4 v = *((const uint4*)((const u16*)in_ + base) + tid);
    float* d = xs + tid * 8;
    d[0] = b2f((u16)(v.x & 0xFFFF)); d[1] = b2f((u16)(v.x >> 16));
    d[2] = b2f((u16)(v.y & 0xFFFF)); d[3] = b2f((u16)(v.y >> 16));
    d[4] = b2f((u16)(v.z & 0xFFFF)); d[5] = b2f((u16)(v.z >> 16));
    d[6] = b2f((u16)(v.w & 0xFFFF)); d[7] = b2f((u16)(v.w >> 16));
  } else {
    const float* in = (const float*)in_;
#pragma unroll
    for (int i = 0; i < 2; ++i) {
      int idx = tid + (i << 8);
      float4 v = ((const float4*)(in + base))[idx];
      int f = (idx & 63) << 2;
      float4 a4 = *(const float4*)(aff + f);
      float4 b4 = *(const float4*)(bff + f);
      v.x = fmaf(a4.x, v.x, b4.x);
      v.y = fmaf(a4.y, v.y, b4.y);
      v.z = fmaf(a4.z, v.z, b4.z);
      v.w = fmaf(a4.w, v.w, b4.w);
      ((float4*)xs)[idx] = v;
    }
  }
  __syncthreads();

  const int nl = tid >> 5, c = tid & 31;
  float accP[8], accQ[8], accR[8];
  {
    float bP = bg[c], bQ = bg[32 + c], bR = bg[64 + c];
#pragma unroll
    for (int t = 0; t < 8; ++t) { accP[t] = bP; accQ[t] = bQ; accR[t] = bR; }
  }
  const float* xrow = xs + (nl << 8);
  for (int ci = 0; ci < 32; ++ci) {
    float4 xa = *(const float4*)(xrow + ci * 8);
    float4 xb = *(const float4*)(xrow + ci * 8 + 4);
    float xv[8] = {xa.x, xa.y, xa.z, xa.w, xb.x, xb.y, xb.z, xb.w};
    const float* wb0 = wl + ci * 99 + c;
    {
      float w0 = wb0[0], w1 = wb0[33], w2 = wb0[66];
      CONV_STEP(accP, w0, w1, w2)
    }
    {
      const float* wb = wb0 + 3168;
      float w0 = wb[0], w1 = wb[33], w2 = wb[66];
      CONV_STEP(accQ, w0, w1, w2)
    }
    {
      const float* wb = wb0 + 6336;
      float w0 = wb[0], w1 = wb[33], w2 = wb[66];
      CONV_STEP(accR, w0, w1, w2)
    }
  }
  float hv[8];
  float hsum = 0.0f, hsq = 0.0f;
#pragma unroll
  for (int t = 0; t < 8; ++t) {
    float q = 1.0f / (1.0f + expf(-accQ[t]));
    float h = fmaxf(accP[t] * q + accR[t], 0.0f);
    hv[t] = h; hsum += h; hsq += h * h;
  }
  {
    uint4 o;
    o.x = pack2(hv[0], hv[1]); o.y = pack2(hv[2], hv[3]);
    o.z = pack2(hv[4], hv[5]); o.w = pack2(hv[6], hv[7]);
    *(uint4*)(out + base + tid * 8) = o;
  }
  float o1 = hsum + __shfl_down(hsum, 32);
  float o2 = hsq + __shfl_down(hsq, 32);
  int wave = tid >> 6, lane = tid & 63;
  if (lane < 32) { red1[wave * 32 + lane] = o1; red2[wave * 32 + lane] = o2; }
  __syncthreads();
  if (tid < 32) {
    float a = red1[tid] + red1[32 + tid] + red1[64 + tid] + red1[96 + tid];
    float b = red2[tid] + red2[32 + tid] + red2[64 + tid] + red2[96 + tid];
    atomicAdd(s1 + tid, a);
    atomicAdd(s2 + tid, b);
  }
}

// ---------------------------------------------------------------- bn finalize
__global__ void k_bnfin(const float* __restrict__ s1, const float* __restrict__ s2,
                        const float* __restrict__ g, const float* __restrict__ b,
                        float cntInv, int nf, int expand,
                        float* __restrict__ A, float* __restrict__ B)
{
  int f = threadIdx.x;
  if (f < nf) {
    int c = expand ? (f >> 3) : f;
    float m = s1[c] * cntInv;
    float var = s2[c] * cntInv - m * m;
    float a = g[c] / sqrtf(var + EPSF);
    A[f] = a;
    B[f] = b[c] - m * a;
  }
}

// ---------------------------------------------------------------- GEMM (in-place, bf16)
// hw = (bf16A*aff+bff) @ W ; writes bf16 A in place; gout = dinv^2 * hw (fp32)
__global__ __launch_bounds__(256) void k_gemm(
    u16* __restrict__ A, const float* __restrict__ W,
    const float* __restrict__ aff, const float* __restrict__ bff,
    const float* __restrict__ dinv, float* __restrict__ gout)
{
  __shared__ float a_lds[32 * 65];
  __shared__ float b_lds[32 * 256];
  const int tid = threadIdx.x;
  const int n0 = blockIdx.x * 64;
  const int rg = tid >> 5;   // 0..7 -> rows rg*8..+7
  const int cg = tid & 31;   // cols cg*4..+3 and 128+cg*4..+3
  float acc[8][8];
#pragma unroll
  for (int i = 0; i < 8; ++i)
#pragma unroll
    for (int j = 0; j < 8; ++j) acc[i][j] = 0.0f;

  for (int k0 = 0; k0 < 256; k0 += 32) {
    if (k0) __syncthreads();
    {
      int r = tid >> 2;               // 0..63
      int cc = (tid & 3) << 3;        // 0,8,16,24
      int n = n0 + r;
      float xv[8];
      if (n < NN) {
        uint4 v = *(const uint4*)(A + (long)n * 256 + k0 + cc);
        xv[0] = b2f((u16)(v.x & 0xFFFF)); xv[1] = b2f((u16)(v.x >> 16));
        xv[2] = b2f((u16)(v.y & 0xFFFF)); xv[3] = b2f((u16)(v.y >> 16));
        xv[4] = b2f((u16)(v.z & 0xFFFF)); xv[5] = b2f((u16)(v.z >> 16));
        xv[6] = b2f((u16)(v.w & 0xFFFF)); xv[7] = b2f((u16)(v.w >> 16));
      } else {
#pragma unroll
        for (int j = 0; j < 8; ++j) xv[j] = 0.0f;
      }
#pragma unroll
      for (int j = 0; j < 8; ++j) {
        a_lds[(cc + j) * 65 + r] = fmaf(aff[k0 + cc + j], xv[j], bff[k0 + cc + j]);
      }
    }
#pragma unroll
    for (int i = 0; i < 8; ++i) {
      int fid = (i << 8) + tid;        // float4 units, 0..2047
      int r = fid >> 6;
      int c4 = fid & 63;
      float4 v = *(const float4*)(W + (long)(k0 + r) * 256 + (c4 << 2));
      *(float4*)(b_lds + (r << 8) + (c4 << 2)) = v;
    }
    __syncthreads();
#pragma unroll
    for (int k = 0; k < 32; ++k) {
      const float* ap = a_lds + k * 65 + (rg << 3);
      const float* bp = b_lds + (k << 8) + (cg << 2);
      float4 a0 = *(const float4*)ap;
      float4 a1 = *(const float4*)(ap + 4);
      float4 b0 = *(const float4*)bp;
      float4 b1 = *(const float4*)(bp + 128);
      float av[8] = {a0.x, a0.y, a0.z, a0.w, a1.x, a1.y, a1.z, a1.w};
      float bv[8] = {b0.x, b0.y, b0.z, b0.w, b1.x, b1.y, b1.z, b1.w};
#pragma unroll
      for (int i = 0; i < 8; ++i)
#pragma unroll
        for (int j = 0; j < 8; ++j) acc[i][j] += av[i] * bv[j];
    }
  }
#pragma unroll
  for (int i = 0; i < 8; ++i) {
    int n = n0 + (rg << 3) + i;
    if (n < NN) {
      float d2 = dinv[n]; d2 *= d2;
      long rb = (long)n * 256 + (cg << 2);
      uint2 s0, s1v;
      s0.x = pack2(acc[i][0], acc[i][1]); s0.y = pack2(acc[i][2], acc[i][3]);
      s1v.x = pack2(acc[i][4], acc[i][5]); s1v.y = pack2(acc[i][6], acc[i][7]);
      *(uint2*)(A + rb) = s0;
      *(uint2*)(A + rb + 128) = s1v;
      *(float4*)(gout + rb) = make_float4(d2 * acc[i][0], d2 * acc[i][1], d2 * acc[i][2], d2 * acc[i][3]);
      *(float4*)(gout + rb + 128) = make_float4(d2 * acc[i][4], d2 * acc[i][5], d2 * acc[i][6], d2 * acc[i][7]);
    }
  }
}

// ---------------------------------------------------------------- edge scatter
__global__ __launch_bounds__(256) void k_scatter(
    const u16* __restrict__ hw, float* __restrict__ gout,
    const int* __restrict__ src, const int* __restrict__ dst,
    const float* __restrict__ dinv)
{
  long gid = (long)blockIdx.x * 256 + threadIdx.x;
  int e = (int)(gid >> 6);
  int c4 = ((int)gid & 63) << 2;
  int s = src[e], d = dst[e];
  float nr = dinv[s] * dinv[d];
  uint2 v = *(const uint2*)(hw + (long)s * 256 + c4);
  float* gp = gout + (long)d * 256 + c4;
  atomicAdd(gp + 0, nr * b2f((u16)(v.x & 0xFFFF)));
  atomicAdd(gp + 1, nr * b2f((u16)(v.x >> 16)));
  atomicAdd(gp + 2, nr * b2f((u16)(v.y & 0xFFFF)));
  atomicAdd(gp + 3, nr * b2f((u16)(v.y >> 16)));
}

// ---------------------------------------------------------------- per-feature col stats
__global__ void k_colstats(const float* __restrict__ x, int rows,
                           float* __restrict__ s1, float* __restrict__ s2)
{
  int f = threadIdx.x;   // 256
  float a = 0.0f, b = 0.0f;
  for (int n = blockIdx.x; n < rows; n += gridDim.x) {
    float v = x[(long)n * 256 + f];
    a += v; b += v * v;
  }
  atomicAdd(s1 + f, a);
  atomicAdd(s2 + f, b);
}

// ---------------------------------------------------------------- finalize layer
// out = a2[c]*h2 + b2[c] + residual(x);  mode 0: relu + in-place bf16 x write
// mode 1: write only t=7 slice to xl (fp32)
__global__ __launch_bounds__(256) void k_final(
    u16* __restrict__ x, const u16* __restrict__ h2,
    const float* __restrict__ resW, const float* __restrict__ resb,
    const float* __restrict__ A2, const float* __restrict__ B2,
    float* __restrict__ xl, int mode)
{
  __shared__ float xs[2048];
  __shared__ float wr[32 * 33];
  const int tid = threadIdx.x;
  for (int idx = tid; idx < 1024; idx += 256) {
    int co = idx >> 5, ci = idx & 31;
    wr[ci * 33 + co] = resW[idx];
  }
  const long base = (long)blockIdx.x * 2048;
  {
    const uint4 v = *((const uint4*)(x + base) + tid);
    float* d = xs + tid * 8;
    d[0] = b2f((u16)(v.x & 0xFFFF)); d[1] = b2f((u16)(v.x >> 16));
    d[2] = b2f((u16)(v.y & 0xFFFF)); d[3] = b2f((u16)(v.y >> 16));
    d[4] = b2f((u16)(v.z & 0xFFFF)); d[5] = b2f((u16)(v.z >> 16));
    d[6] = b2f((u16)(v.w & 0xFFFF)); d[7] = b2f((u16)(v.w >> 16));
  }
  __syncthreads();
  const int nl = tid >> 5, c = tid & 31;
  float r[8];
  {
    float rb = resb[c];
#pragma unroll
    for (int t = 0; t < 8; ++t) r[t] = rb;
  }
  const float* xrow = xs + (nl << 8);
  for (int ci = 0; ci < 32; ++ci) {
    float w = wr[ci * 33 + c];
    float4 xa = *(const float4*)(xrow + ci * 8);
    float4 xb = *(const float4*)(xrow + ci * 8 + 4);
    r[0] += xa.x * w; r[1] += xa.y * w; r[2] += xa.z * w; r[3] += xa.w * w;
    r[4] += xb.x * w; r[5] += xb.y * w; r[6] += xb.z * w; r[7] += xb.w * w;
  }
  float a2 = A2[c], b2 = B2[c];
  float hv[8];
  {
    const uint4 v = *((const uint4*)(h2 + base) + tid);
    hv[0] = b2f((u16)(v.x & 0xFFFF)); hv[1] = b2f((u16)(v.x >> 16));
    hv[2] = b2f((u16)(v.y & 0xFFFF)); hv[3] = b2f((u16)(v.y >> 16));
    hv[4] = b2f((u16)(v.z & 0xFFFF)); hv[5] = b2f((u16)(v.z >> 16));
    hv[6] = b2f((u16)(v.w & 0xFFFF)); hv[7] = b2f((u16)(v.w >> 16));
  }
  if (mode == 0) {
    uint4 o;
    float ov[8];
#pragma unroll
    for (int t = 0; t < 8; ++t) ov[t] = fmaxf(fmaf(a2, hv[t], b2) + r[t], 0.0f);
    o.x = pack2(ov[0], ov[1]); o.y = pack2(ov[2], ov[3]);
    o.z = pack2(ov[4], ov[5]); o.w = pack2(ov[6], ov[7]);
    *(uint4*)(x + base + tid * 8) = o;
  } else {
    float v = fmaf(a2, hv[7], b2) + r[7];
    int n = blockIdx.x * 8 + nl;
    xl[n * 32 + c] = v;
  }
}

// ---------------------------------------------------------------- pooling
__global__ void k_pool(const float* __restrict__ xl, const int* __restrict__ graphs,
                       int* __restrict__ cnt, float* __restrict__ sp,
                       unsigned* __restrict__ mxu)
{
  int gid = blockIdx.x * 256 + threadIdx.x;  // N*32
  int n = gid >> 5, c = gid & 31;
  int g = graphs[n];
  float v = xl[gid];
  atomicAdd(sp + g * 32 + c, v);
  unsigned u = __float_as_uint(v);
  u = (u & 0x80000000u) ? ~u : (u | 0x80000000u);
  atomicMax(mxu + g * 32 + c, u);
  if (c == 0) atomicAdd(cnt + g, 1);
}

// ---------------------------------------------------------------- MLP head
__global__ __launch_bounds__(128) void k_head(
    const int* __restrict__ cnt, const float* __restrict__ sp,
    const unsigned* __restrict__ mxu,
    const float* __restrict__ W1, const float* __restrict__ b1,
    const float* __restrict__ W2, const float* __restrict__ b2,
    const float* __restrict__ W3, const float* __restrict__ b3,
    float* __restrict__ out)
{
  __shared__ float xg[96], hh1[128], hh2[64];
  const int g = blockIdx.x, tid = threadIdx.x;
  if (tid < 32) {
    float s = sp[g * 32 + tid];
    int cn = cnt[g];
    float mean = s / fmaxf((float)cn, 1.0f);
    float mx = 0.0f;
    if (cn > 0) {
      unsigned u = mxu[g * 32 + tid];
      unsigned ub = (u & 0x80000000u) ? (u ^ 0x80000000u) : ~u;
      mx = __uint_as_float(ub);
    }
    xg[tid] = mean; xg[32 + tid] = mx; xg[64 + tid] = s;
  }
  __syncthreads();
  {
    float a = b1[tid];
    for (int k = 0; k < 96; ++k) a += xg[k] * W1[k * 128 + tid];
    hh1[tid] = fmaxf(a, 0.0f);
  }
  __syncthreads();
  if (tid < 64) {
    float a = b2[tid];
    for (int k = 0; k < 128; ++k) a += hh1[k] * W2[k * 64 + tid];
    hh2[tid] = fmaxf(a, 0.0f);
  }
  __syncthreads();
  if (tid < 64) {
    float p = hh2[tid] * W3[tid];
    for (int off = 32; off; off >>= 1) p += __shfl_down(p, off);
    if (tid == 0) out[g] = p + b3[0];
  }
}

// ================================================================ launch
extern "C" void kernel_launch(void* const* d_in, const int* in_sizes, int n_in,
                              void* d_out, int out_size, void* d_ws, size_t ws_size,
                              hipStream_t stream)
{
  const float* X       = (const float*)d_in[0];
  const int*   edge    = (const int*)d_in[1];
  const int*   graphs  = (const int*)d_in[2];
  const float* W_in    = (const float*)d_in[3];
  const float* b_in    = (const float*)d_in[4];
  const float* res_W   = (const float*)d_in[5];
  const float* res_b   = (const float*)d_in[6];
  const float* g1_W    = (const float*)d_in[7];
  const float* g1_b    = (const float*)d_in[8];
  const float* bn0_g   = (const float*)d_in[9];
  const float* bn0_b   = (const float*)d_in[10];
  const float* gcn_W   = (const float*)d_in[11];
  // d_in[12] = gcn_b: cancels in bn1 (per-feature shift removed by mean over axis 0)
  const float* bn1_g   = (const float*)d_in[13];
  const float* bn1_b   = (const float*)d_in[14];
  const float* g2_W    = (const float*)d_in[15];
  const float* g2_b    = (const float*)d_in[16];
  const float* bn2_g   = (const float*)d_in[17];
  const float* bn2_b   = (const float*)d_in[18];
  const float* out_W1  = (const float*)d_in[19];
  const float* out_b1  = (const float*)d_in[20];
  const float* out_W2  = (const float*)d_in[21];
  const float* out_b2  = (const float*)d_in[22];
  const float* out_W3  = (const float*)d_in[23];
  const float* out_b3  = (const float*)d_in[24];
  float* outp = (float*)d_out;

  const int* srcp = edge;
  const int* dstp = edge + EE;

  // ---- workspace layout (bf16 activations; ~109 MB total) ----
  const long BIGE = (long)NN * 256;              // 12.8M elems
  u16*   P0   = (u16*)d_ws;                      // x, bf16      25.6 MB
  u16*   P1   = P0 + BIGE;                       // h1/hw, bf16  25.6 MB
  float* P2   = (float*)(P1 + BIGE);             // g, fp32      51.2 MB
  float* xl   = P2 + BIGE;                       // N*32 fp32     6.4 MB
  float* dinv = xl + (long)NN * 32;              // N
  int*   degi = (int*)(dinv + NN);               // N      <- zero region start
  float* stats = dinv + 2 * NN;                  // 1280 (2 layers x 640)
  int*   cnt  = (int*)(stats + 1280);            // 64
  float* sp   = stats + 1280 + 64;               // 2048
  unsigned* mxu = (unsigned*)(sp + 2048);        // 2048   <- zero region end
  float* AFF  = sp + 2048 + 2048;                // 256
  float* BFF  = AFF + 256;
  float* A2v  = BFF + 256;
  float* B2v  = A2v + 32;

  const size_t zero_bytes = (size_t)(NN + 1280 + 64 + 2048 + 2048) * 4;
  hipMemsetAsync(degi, 0, zero_bytes, stream);

  k_convin<<<NN / 8, 256, 0, stream>>>(X, P0, W_in, b_in);
  k_deg<<<(EE + 255) / 256, 256, 0, stream>>>(dstp, degi);
  k_dinv<<<(NN + 255) / 256, 256, 0, stream>>>(degi, dinv);

  for (int l = 0; l < 2; ++l) {
    const float* g1Wl = g1_W + l * 9216;
    const float* g1bl = g1_b + l * 96;
    const float* g2Wl = g2_W + l * 9216;
    const float* g2bl = g2_b + l * 96;
    float* st = stats + l * 640;

    // gated conv 1 (bf16 input, no fold) + bn0 stats
    k_gated<1><<<NN / 8, 256, 0, stream>>>(P0, P1, g1Wl, g1bl,
                                           (const float*)nullptr, (const float*)nullptr,
                                           st + 0, st + 32);
    k_bnfin<<<1, 256, 0, stream>>>(st + 0, st + 32, bn0_g + l * 32, bn0_b + l * 32,
                                   1.0f / 400000.0f, 256, 1, AFF, BFF);
    // GEMM with bn0 fold on A-load; in-place bf16; self-loop init of P2
    k_gemm<<<(NN + 63) / 64, 256, 0, stream>>>(P1, gcn_W + l * 65536, AFF, BFF, dinv, P2);
    // edge scatter (bf16 reads, fp32 atomics)
    k_scatter<<<(EE * 64) / 256, 256, 0, stream>>>(P1, P2, srcp, dstp, dinv);
    // bn1 stats + fold (gcn bias cancels in bn1)
    k_colstats<<<512, 256, 0, stream>>>(P2, NN, st + 64, st + 320);
    k_bnfin<<<1, 256, 0, stream>>>(st + 64, st + 320, bn1_g + l * 256, bn1_b + l * 256,
                                   1.0f / (float)NN, 256, 0, AFF, BFF);
    // gated conv 2 (fp32 input, bn1 fold) + bn2 stats
    k_gated<0><<<NN / 8, 256, 0, stream>>>(P2, P1, g2Wl, g2bl, AFF, BFF, st + 576, st + 608);
    k_bnfin<<<1, 256, 0, stream>>>(st + 576, st + 608, bn2_g + l * 32, bn2_b + l * 32,
                                   1.0f / 400000.0f, 32, 0, A2v, B2v);
    // finalize: bn2 + residual(x) + (relu in-place | t=7 slice)
    k_final<<<NN / 8, 256, 0, stream>>>(P0, P1, res_W + l * 1024, res_b + l * 32,
                                        A2v, B2v, xl, (l == 0) ? 0 : 1);
  }

  k_pool<<<NN * 32 / 256, 256, 0, stream>>>(xl, graphs, cnt, sp, mxu);
  k_head<<<64, 128, 0, stream>>>(cnt, sp, mxu, out_W1, out_b1, out_W2, out_b2,
                                 out_W3, out_b3, outp);

  (void)in_sizes; (void)n_in; (void)out_size; (void)ws_size;
}

// Round 3
// 2036.838 us; speedup vs baseline: 2.0862x; 2.0862x over previous
//
#include <hip/hip_runtime.h>
#include <hip/hip_bf16.h>

#define NN 50000
#define EE 400000
#define EPSF 1e-5f

typedef unsigned short u16;
__device__ __forceinline__ float b2f(u16 u) { return __uint_as_float(((unsigned)u) << 16); }
__device__ __forceinline__ u16 f2b(float f) {
  unsigned x = __float_as_uint(f);
  unsigned r = x + 0x7FFFu + ((x >> 16) & 1u);   // RNE
  return (u16)(r >> 16);
}
__device__ __forceinline__ unsigned pack2(float lo, float hi) {
  return (unsigned)f2b(lo) | ((unsigned)f2b(hi) << 16);
}

// ---------------------------------------------------------------- conv_in
// x0[n,c,t] = sum_ci X[n,ci,t]*W[c,ci] + b[c]   (N,16,8)fp32 -> (N,32,8)bf16
__global__ __launch_bounds__(256) void k_convin(
    const float* __restrict__ X, u16* __restrict__ out,
    const float* __restrict__ Wi, const float* __restrict__ bi)
{
  __shared__ float xs[1024];      // 8 nodes x 128
  __shared__ float wi[16 * 33];   // [ci][co] padded
  const int tid = threadIdx.x;
  for (int idx = tid; idx < 512; idx += 256) {
    int co = idx >> 4, ci = idx & 15;
    wi[ci * 33 + co] = Wi[idx];
  }
  const long xbase = (long)blockIdx.x * 1024;
  ((float4*)xs)[tid] = ((const float4*)(X + xbase))[tid];
  __syncthreads();
  const int nl = tid >> 5, c = tid & 31;
  float acc[8];
  {
    float bc = bi[c];
#pragma unroll
    for (int t = 0; t < 8; ++t) acc[t] = bc;
  }
  const float* xrow = xs + (nl << 7);
  for (int ci = 0; ci < 16; ++ci) {
    float w = wi[ci * 33 + c];
    float4 xa = *(const float4*)(xrow + ci * 8);
    float4 xb = *(const float4*)(xrow + ci * 8 + 4);
    acc[0] += xa.x * w; acc[1] += xa.y * w; acc[2] += xa.z * w; acc[3] += xa.w * w;
    acc[4] += xb.x * w; acc[5] += xb.y * w; acc[6] += xb.z * w; acc[7] += xb.w * w;
  }
  uint4 o;
  o.x = pack2(acc[0], acc[1]); o.y = pack2(acc[2], acc[3]);
  o.z = pack2(acc[4], acc[5]); o.w = pack2(acc[6], acc[7]);
  *(uint4*)(out + (long)blockIdx.x * 2048 + tid * 8) = o;
}

// ---------------------------------------------------------------- degree / dinv
__global__ void k_deg(const int* __restrict__ dst, int* __restrict__ degi)
{
  int e = blockIdx.x * 256 + threadIdx.x;
  if (e < EE) atomicAdd(degi + dst[e], 1);
}
__global__ void k_dinv(const int* __restrict__ degi, float* __restrict__ dinv)
{
  int n = blockIdx.x * 256 + threadIdx.x;
  if (n < NN) dinv[n] = rsqrtf((float)degi[n] + 1.0f);
}

// ---------------------------------------------------------------- CSR build
// single-block exclusive scan of degi -> rowptr & cursor
__global__ __launch_bounds__(1024) void k_scan(const int* __restrict__ degi,
                                               int* __restrict__ rowptr,
                                               int* __restrict__ cursor)
{
  __shared__ int wsum[16];
  __shared__ int carry;
  const int tid = threadIdx.x, lane = tid & 63, wv = tid >> 6;
  if (tid == 0) carry = 0;
  __syncthreads();
  for (int base = 0; base < NN; base += 1024) {
    int i = base + tid;
    int v = (i < NN) ? degi[i] : 0;
    int s = v;
#pragma unroll
    for (int d = 1; d < 64; d <<= 1) { int t = __shfl_up(s, d); if (lane >= d) s += t; }
    if (lane == 63) wsum[wv] = s;
    __syncthreads();
    if (tid < 16) {
      int ws = wsum[tid];
#pragma unroll
      for (int d = 1; d < 16; d <<= 1) { int t = __shfl_up(ws, d, 16); if (tid >= d) ws += t; }
      wsum[tid] = ws;
    }
    __syncthreads();
    int excl = carry + (wv ? wsum[wv - 1] : 0) + (s - v);
    if (i < NN) { rowptr[i] = excl; cursor[i] = excl; }
    __syncthreads();
    if (tid == 0) carry += wsum[15];
    __syncthreads();
  }
  if (tid == 0) rowptr[NN] = carry;
}

__global__ void k_fill(const int* __restrict__ src, const int* __restrict__ dst,
                       const float* __restrict__ dinv,
                       int* __restrict__ cursor,
                       int* __restrict__ eidx, float* __restrict__ enrm)
{
  int e = blockIdx.x * 256 + threadIdx.x;
  if (e < EE) {
    int s = src[e], d = dst[e];
    int p = atomicAdd(cursor + d, 1);
    eidx[p] = s;
    enrm[p] = dinv[s] * dinv[d];
  }
}

// ---------------------------------------------------------------- GCN gather
// out[d,:] = dinv[d]^2*hw[d,:] + sum_{e: dst=d} nr_e * hw[src_e,:]
// one wave per dst node; lane handles 4 consecutive features
__global__ __launch_bounds__(256) void k_gather(
    const u16* __restrict__ hw, float* __restrict__ out,
    const int* __restrict__ rowptr, const int* __restrict__ eidx,
    const float* __restrict__ enrm, const float* __restrict__ dinv)
{
  const int wid = (blockIdx.x << 2) + (threadIdx.x >> 6);
  if (wid >= NN) return;
  const int lane = threadIdx.x & 63;
  const int c0 = lane << 2;
  float a0, a1, a2, a3;
  {
    float d2 = dinv[wid]; d2 *= d2;
    uint2 v = *(const uint2*)(hw + (long)wid * 256 + c0);
    a0 = d2 * b2f((u16)(v.x & 0xFFFF)); a1 = d2 * b2f((u16)(v.x >> 16));
    a2 = d2 * b2f((u16)(v.y & 0xFFFF)); a3 = d2 * b2f((u16)(v.y >> 16));
  }
  int p = rowptr[wid];
  const int end = rowptr[wid + 1];
  for (; p + 1 < end; p += 2) {
    int s0 = eidx[p], s1 = eidx[p + 1];
    float n0 = enrm[p], n1 = enrm[p + 1];
    uint2 v0 = *(const uint2*)(hw + (long)s0 * 256 + c0);
    uint2 v1 = *(const uint2*)(hw + (long)s1 * 256 + c0);
    a0 += n0 * b2f((u16)(v0.x & 0xFFFF)) + n1 * b2f((u16)(v1.x & 0xFFFF));
    a1 += n0 * b2f((u16)(v0.x >> 16))    + n1 * b2f((u16)(v1.x >> 16));
    a2 += n0 * b2f((u16)(v0.y & 0xFFFF)) + n1 * b2f((u16)(v1.y & 0xFFFF));
    a3 += n0 * b2f((u16)(v0.y >> 16))    + n1 * b2f((u16)(v1.y >> 16));
  }
  if (p < end) {
    int s0 = eidx[p];
    float n0 = enrm[p];
    uint2 v0 = *(const uint2*)(hw + (long)s0 * 256 + c0);
    a0 += n0 * b2f((u16)(v0.x & 0xFFFF));
    a1 += n0 * b2f((u16)(v0.x >> 16));
    a2 += n0 * b2f((u16)(v0.y & 0xFFFF));
    a3 += n0 * b2f((u16)(v0.y >> 16));
  }
  *(float4*)(out + (long)wid * 256 + c0) = make_float4(a0, a1, a2, a3);
}

// ---------------------------------------------------------------- gated conv
// out(bf16) = relu(P * sigmoid(Q) + R); k=3 pad=1 over t; per-channel stats.
#define CONV_STEP(ACC, W0, W1, W2)                    \
  ACC[0] += xv[0]*W1 + xv[1]*W2;                      \
  ACC[1] += xv[0]*W0 + xv[1]*W1 + xv[2]*W2;           \
  ACC[2] += xv[1]*W0 + xv[2]*W1 + xv[3]*W2;           \
  ACC[3] += xv[2]*W0 + xv[3]*W1 + xv[4]*W2;           \
  ACC[4] += xv[3]*W0 + xv[4]*W1 + xv[5]*W2;           \
  ACC[5] += xv[4]*W0 + xv[5]*W1 + xv[6]*W2;           \
  ACC[6] += xv[5]*W0 + xv[6]*W1 + xv[7]*W2;           \
  ACC[7] += xv[6]*W0 + xv[7]*W1;

template<int INBF>
__global__ __launch_bounds__(256) void k_gated(
    const void* __restrict__ in_, u16* __restrict__ out,
    const float* __restrict__ Wg,   // (3,32,32,3)
    const float* __restrict__ bg,   // (3,32)
    const float* __restrict__ aff, const float* __restrict__ bff, // per-f (256) or null
    float* __restrict__ s1, float* __restrict__ s2)               // [32]
{
  __shared__ float xs[2048];
  __shared__ float wl[3 * 96 * 33];
  __shared__ float red1[128], red2[128];
  const int tid = threadIdx.x;

  for (int idx = tid; idx < 9216; idx += 256) {
    int conv = idx / 3072;
    int r = idx - conv * 3072;
    int co = r / 96;
    int r2 = r - co * 96;                 // ci*3+dt
    wl[conv * 3168 + r2 * 33 + co] = Wg[idx];
  }
  const long base = (long)blockIdx.x * 2048;
  if (INBF) {
    const uint4 v = *((const uint4*)((const u16*)in_ + base) + tid);
    float* d = xs + tid * 8;
    d[0] = b2f((u16)(v.x & 0xFFFF)); d[1] = b2f((u16)(v.x >> 16));
    d[2] = b2f((u16)(v.y & 0xFFFF)); d[3] = b2f((u16)(v.y >> 16));
    d[4] = b2f((u16)(v.z & 0xFFFF)); d[5] = b2f((u16)(v.z >> 16));
    d[6] = b2f((u16)(v.w & 0xFFFF)); d[7] = b2f((u16)(v.w >> 16));
  } else {
    const float* in = (const float*)in_;
#pragma unroll
    for (int i = 0; i < 2; ++i) {
      int idx = tid + (i << 8);
      float4 v = ((const float4*)(in + base))[idx];
      int f = (idx & 63) << 2;
      float4 a4 = *(const float4*)(aff + f);
      float4 b4 = *(const float4*)(bff + f);
      v.x = fmaf(a4.x, v.x, b4.x);
      v.y = fmaf(a4.y, v.y, b4.y);
      v.z = fmaf(a4.z, v.z, b4.z);
      v.w = fmaf(a4.w, v.w, b4.w);
      ((float4*)xs)[idx] = v;
    }
  }
  __syncthreads();

  const int nl = tid >> 5, c = tid & 31;
  float accP[8], accQ[8], accR[8];
  {
    float bP = bg[c], bQ = bg[32 + c], bR = bg[64 + c];
#pragma unroll
    for (int t = 0; t < 8; ++t) { accP[t] = bP; accQ[t] = bQ; accR[t] = bR; }
  }
  const float* xrow = xs + (nl << 8);
  for (int ci = 0; ci < 32; ++ci) {
    float4 xa = *(const float4*)(xrow + ci * 8);
    float4 xb = *(const float4*)(xrow + ci * 8 + 4);
    float xv[8] = {xa.x, xa.y, xa.z, xa.w, xb.x, xb.y, xb.z, xb.w};
    const float* wb0 = wl + ci * 99 + c;
    {
      float w0 = wb0[0], w1 = wb0[33], w2 = wb0[66];
      CONV_STEP(accP, w0, w1, w2)
    }
    {
      const float* wb = wb0 + 3168;
      float w0 = wb[0], w1 = wb[33], w2 = wb[66];
      CONV_STEP(accQ, w0, w1, w2)
    }
    {
      const float* wb = wb0 + 6336;
      float w0 = wb[0], w1 = wb[33], w2 = wb[66];
      CONV_STEP(accR, w0, w1, w2)
    }
  }
  float hv[8];
  float hsum = 0.0f, hsq = 0.0f;
#pragma unroll
  for (int t = 0; t < 8; ++t) {
    float q = 1.0f / (1.0f + expf(-accQ[t]));
    float h = fmaxf(accP[t] * q + accR[t], 0.0f);
    hv[t] = h; hsum += h; hsq += h * h;
  }
  {
    uint4 o;
    o.x = pack2(hv[0], hv[1]); o.y = pack2(hv[2], hv[3]);
    o.z = pack2(hv[4], hv[5]); o.w = pack2(hv[6], hv[7]);
    *(uint4*)(out + base + tid * 8) = o;
  }
  float o1 = hsum + __shfl_down(hsum, 32);
  float o2 = hsq + __shfl_down(hsq, 32);
  int wave = tid >> 6, lane = tid & 63;
  if (lane < 32) { red1[wave * 32 + lane] = o1; red2[wave * 32 + lane] = o2; }
  __syncthreads();
  if (tid < 32) {
    float a = red1[tid] + red1[32 + tid] + red1[64 + tid] + red1[96 + tid];
    float b = red2[tid] + red2[32 + tid] + red2[64 + tid] + red2[96 + tid];
    atomicAdd(s1 + tid, a);
    atomicAdd(s2 + tid, b);
  }
}

// ---------------------------------------------------------------- bn finalize
__global__ void k_bnfin(const float* __restrict__ s1, const float* __restrict__ s2,
                        const float* __restrict__ g, const float* __restrict__ b,
                        float cntInv, int nf, int expand,
                        float* __restrict__ A, float* __restrict__ B)
{
  int f = threadIdx.x;
  if (f < nf) {
    int c = expand ? (f >> 3) : f;
    float m = s1[c] * cntInv;
    float var = s2[c] * cntInv - m * m;
    float a = g[c] / sqrtf(var + EPSF);
    A[f] = a;
    B[f] = b[c] - m * a;
  }
}

// ---------------------------------------------------------------- GEMM (in-place, bf16)
// hw = (bf16A*aff+bff) @ W ; writes bf16 A in place
__global__ __launch_bounds__(256) void k_gemm(
    u16* __restrict__ A, const float* __restrict__ W,
    const float* __restrict__ aff, const float* __restrict__ bff)
{
  __shared__ float a_lds[32 * 65];
  __shared__ float b_lds[32 * 256];
  const int tid = threadIdx.x;
  const int n0 = blockIdx.x * 64;
  const int rg = tid >> 5;   // 0..7 -> rows rg*8..+7
  const int cg = tid & 31;   // cols cg*4..+3 and 128+cg*4..+3
  float acc[8][8];
#pragma unroll
  for (int i = 0; i < 8; ++i)
#pragma unroll
    for (int j = 0; j < 8; ++j) acc[i][j] = 0.0f;

  for (int k0 = 0; k0 < 256; k0 += 32) {
    if (k0) __syncthreads();
    {
      int r = tid >> 2;               // 0..63
      int cc = (tid & 3) << 3;        // 0,8,16,24
      int n = n0 + r;
      float xv[8];
      if (n < NN) {
        uint4 v = *(const uint4*)(A + (long)n * 256 + k0 + cc);
        xv[0] = b2f((u16)(v.x & 0xFFFF)); xv[1] = b2f((u16)(v.x >> 16));
        xv[2] = b2f((u16)(v.y & 0xFFFF)); xv[3] = b2f((u16)(v.y >> 16));
        xv[4] = b2f((u16)(v.z & 0xFFFF)); xv[5] = b2f((u16)(v.z >> 16));
        xv[6] = b2f((u16)(v.w & 0xFFFF)); xv[7] = b2f((u16)(v.w >> 16));
      } else {
#pragma unroll
        for (int j = 0; j < 8; ++j) xv[j] = 0.0f;
      }
#pragma unroll
      for (int j = 0; j < 8; ++j) {
        a_lds[(cc + j) * 65 + r] = fmaf(aff[k0 + cc + j], xv[j], bff[k0 + cc + j]);
      }
    }
#pragma unroll
    for (int i = 0; i < 8; ++i) {
      int fid = (i << 8) + tid;        // float4 units, 0..2047
      int r = fid >> 6;
      int c4 = fid & 63;
      float4 v = *(const float4*)(W + (long)(k0 + r) * 256 + (c4 << 2));
      *(float4*)(b_lds + (r << 8) + (c4 << 2)) = v;
    }
    __syncthreads();
#pragma unroll
    for (int k = 0; k < 32; ++k) {
      const float* ap = a_lds + k * 65 + (rg << 3);
      const float* bp = b_lds + (k << 8) + (cg << 2);
      float4 a0 = *(const float4*)ap;
      float4 a1 = *(const float4*)(ap + 4);
      float4 b0 = *(const float4*)bp;
      float4 b1 = *(const float4*)(bp + 128);
      float av[8] = {a0.x, a0.y, a0.z, a0.w, a1.x, a1.y, a1.z, a1.w};
      float bv[8] = {b0.x, b0.y, b0.z, b0.w, b1.x, b1.y, b1.z, b1.w};
#pragma unroll
      for (int i = 0; i < 8; ++i)
#pragma unroll
        for (int j = 0; j < 8; ++j) acc[i][j] += av[i] * bv[j];
    }
  }
#pragma unroll
  for (int i = 0; i < 8; ++i) {
    int n = n0 + (rg << 3) + i;
    if (n < NN) {
      long rb = (long)n * 256 + (cg << 2);
      uint2 s0, s1v;
      s0.x = pack2(acc[i][0], acc[i][1]); s0.y = pack2(acc[i][2], acc[i][3]);
      s1v.x = pack2(acc[i][4], acc[i][5]); s1v.y = pack2(acc[i][6], acc[i][7]);
      *(uint2*)(A + rb) = s0;
      *(uint2*)(A + rb + 128) = s1v;
    }
  }
}

// ---------------------------------------------------------------- per-feature col stats
__global__ void k_colstats(const float* __restrict__ x, int rows,
                           float* __restrict__ s1, float* __restrict__ s2)
{
  int f = threadIdx.x;   // 256
  float a = 0.0f, b = 0.0f;
  for (int n = blockIdx.x; n < rows; n += gridDim.x) {
    float v = x[(long)n * 256 + f];
    a += v; b += v * v;
  }
  atomicAdd(s1 + f, a);
  atomicAdd(s2 + f, b);
}

// ---------------------------------------------------------------- finalize layer
__global__ __launch_bounds__(256) void k_final(
    u16* __restrict__ x, const u16* __restrict__ h2,
    const float* __restrict__ resW, const float* __restrict__ resb,
    const float* __restrict__ A2, const float* __restrict__ B2,
    float* __restrict__ xl, int mode)
{
  __shared__ float xs[2048];
  __shared__ float wr[32 * 33];
  const int tid = threadIdx.x;
  for (int idx = tid; idx < 1024; idx += 256) {
    int co = idx >> 5, ci = idx & 31;
    wr[ci * 33 + co] = resW[idx];
  }
  const long base = (long)blockIdx.x * 2048;
  {
    const uint4 v = *((const uint4*)(x + base) + tid);
    float* d = xs + tid * 8;
    d[0] = b2f((u16)(v.x & 0xFFFF)); d[1] = b2f((u16)(v.x >> 16));
    d[2] = b2f((u16)(v.y & 0xFFFF)); d[3] = b2f((u16)(v.y >> 16));
    d[4] = b2f((u16)(v.z & 0xFFFF)); d[5] = b2f((u16)(v.z >> 16));
    d[6] = b2f((u16)(v.w & 0xFFFF)); d[7] = b2f((u16)(v.w >> 16));
  }
  __syncthreads();
  const int nl = tid >> 5, c = tid & 31;
  float r[8];
  {
    float rb = resb[c];
#pragma unroll
    for (int t = 0; t < 8; ++t) r[t] = rb;
  }
  const float* xrow = xs + (nl << 8);
  for (int ci = 0; ci < 32; ++ci) {
    float w = wr[ci * 33 + c];
    float4 xa = *(const float4*)(xrow + ci * 8);
    float4 xb = *(const float4*)(xrow + ci * 8 + 4);
    r[0] += xa.x * w; r[1] += xa.y * w; r[2] += xa.z * w; r[3] += xa.w * w;
    r[4] += xb.x * w; r[5] += xb.y * w; r[6] += xb.z * w; r[7] += xb.w * w;
  }
  float a2 = A2[c], b2 = B2[c];
  float hv[8];
  {
    const uint4 v = *((const uint4*)(h2 + base) + tid);
    hv[0] = b2f((u16)(v.x & 0xFFFF)); hv[1] = b2f((u16)(v.x >> 16));
    hv[2] = b2f((u16)(v.y & 0xFFFF)); hv[3] = b2f((u16)(v.y >> 16));
    hv[4] = b2f((u16)(v.z & 0xFFFF)); hv[5] = b2f((u16)(v.z >> 16));
    hv[6] = b2f((u16)(v.w & 0xFFFF)); hv[7] = b2f((u16)(v.w >> 16));
  }
  if (mode == 0) {
    uint4 o;
    float ov[8];
#pragma unroll
    for (int t = 0; t < 8; ++t) ov[t] = fmaxf(fmaf(a2, hv[t], b2) + r[t], 0.0f);
    o.x = pack2(ov[0], ov[1]); o.y = pack2(ov[2], ov[3]);
    o.z = pack2(ov[4], ov[5]); o.w = pack2(ov[6], ov[7]);
    *(uint4*)(x + base + tid * 8) = o;
  } else {
    float v = fmaf(a2, hv[7], b2) + r[7];
    int n = blockIdx.x * 8 + nl;
    xl[n * 32 + c] = v;
  }
}

// ---------------------------------------------------------------- pooling
__global__ void k_pool(const float* __restrict__ xl, const int* __restrict__ graphs,
                       int* __restrict__ cnt, float* __restrict__ sp,
                       unsigned* __restrict__ mxu)
{
  int gid = blockIdx.x * 256 + threadIdx.x;  // N*32
  int n = gid >> 5, c = gid & 31;
  int g = graphs[n];
  float v = xl[gid];
  atomicAdd(sp + g * 32 + c, v);
  unsigned u = __float_as_uint(v);
  u = (u & 0x80000000u) ? ~u : (u | 0x80000000u);
  atomicMax(mxu + g * 32 + c, u);
  if (c == 0) atomicAdd(cnt + g, 1);
}

// ---------------------------------------------------------------- MLP head
__global__ __launch_bounds__(128) void k_head(
    const int* __restrict__ cnt, const float* __restrict__ sp,
    const unsigned* __restrict__ mxu,
    const float* __restrict__ W1, const float* __restrict__ b1,
    const float* __restrict__ W2, const float* __restrict__ b2,
    const float* __restrict__ W3, const float* __restrict__ b3,
    float* __restrict__ out)
{
  __shared__ float xg[96], hh1[128], hh2[64];
  const int g = blockIdx.x, tid = threadIdx.x;
  if (tid < 32) {
    float s = sp[g * 32 + tid];
    int cn = cnt[g];
    float mean = s / fmaxf((float)cn, 1.0f);
    float mx = 0.0f;
    if (cn > 0) {
      unsigned u = mxu[g * 32 + tid];
      unsigned ub = (u & 0x80000000u) ? (u ^ 0x80000000u) : ~u;
      mx = __uint_as_float(ub);
    }
    xg[tid] = mean; xg[32 + tid] = mx; xg[64 + tid] = s;
  }
  __syncthreads();
  {
    float a = b1[tid];
    for (int k = 0; k < 96; ++k) a += xg[k] * W1[k * 128 + tid];
    hh1[tid] = fmaxf(a, 0.0f);
  }
  __syncthreads();
  if (tid < 64) {
    float a = b2[tid];
    for (int k = 0; k < 128; ++k) a += hh1[k] * W2[k * 64 + tid];
    hh2[tid] = fmaxf(a, 0.0f);
  }
  __syncthreads();
  if (tid < 64) {
    float p = hh2[tid] * W3[tid];
    for (int off = 32; off; off >>= 1) p += __shfl_down(p, off);
    if (tid == 0) out[g] = p + b3[0];
  }
}

// ================================================================ launch
extern "C" void kernel_launch(void* const* d_in, const int* in_sizes, int n_in,
                              void* d_out, int out_size, void* d_ws, size_t ws_size,
                              hipStream_t stream)
{
  const float* X       = (const float*)d_in[0];
  const int*   edge    = (const int*)d_in[1];
  const int*   graphs  = (const int*)d_in[2];
  const float* W_in    = (const float*)d_in[3];
  const float* b_in    = (const float*)d_in[4];
  const float* res_W   = (const float*)d_in[5];
  const float* res_b   = (const float*)d_in[6];
  const float* g1_W    = (const float*)d_in[7];
  const float* g1_b    = (const float*)d_in[8];
  const float* bn0_g   = (const float*)d_in[9];
  const float* bn0_b   = (const float*)d_in[10];
  const float* gcn_W   = (const float*)d_in[11];
  // d_in[12] = gcn_b: cancels in bn1 (per-feature shift removed by mean over axis 0)
  const float* bn1_g   = (const float*)d_in[13];
  const float* bn1_b   = (const float*)d_in[14];
  const float* g2_W    = (const float*)d_in[15];
  const float* g2_b    = (const float*)d_in[16];
  const float* bn2_g   = (const float*)d_in[17];
  const float* bn2_b   = (const float*)d_in[18];
  const float* out_W1  = (const float*)d_in[19];
  const float* out_b1  = (const float*)d_in[20];
  const float* out_W2  = (const float*)d_in[21];
  const float* out_b2  = (const float*)d_in[22];
  const float* out_W3  = (const float*)d_in[23];
  const float* out_b3  = (const float*)d_in[24];
  float* outp = (float*)d_out;

  const int* srcp = edge;
  const int* dstp = edge + EE;

  // ---- workspace layout (~113 MB) ----
  const long BIGE = (long)NN * 256;              // 12.8M elems
  u16*   P0   = (u16*)d_ws;                      // x, bf16      25.6 MB
  u16*   P1   = P0 + BIGE;                       // h1/hw, bf16  25.6 MB
  float* P2   = (float*)(P1 + BIGE);             // g, fp32      51.2 MB
  float* xl   = P2 + BIGE;                       // N*32 fp32     6.4 MB
  float* dinv = xl + (long)NN * 32;              // N
  int*   rowptr = (int*)(dinv + NN);             // N+1
  int*   cursor = rowptr + NN + 1;               // N
  int*   eidx   = cursor + NN;                   // E
  float* enrm   = (float*)(eidx + EE);           // E
  int*   degi = (int*)(enrm + EE);               // N      <- zero region start
  float* stats = (float*)(degi + NN);            // 1280 (2 layers x 640)
  int*   cnt  = (int*)(stats + 1280);            // 64
  float* sp   = stats + 1280 + 64;               // 2048
  unsigned* mxu = (unsigned*)(sp + 2048);        // 2048   <- zero region end
  float* AFF  = sp + 2048 + 2048;                // 256
  float* BFF  = AFF + 256;
  float* A2v  = BFF + 256;
  float* B2v  = A2v + 32;

  const size_t zero_bytes = (size_t)(NN + 1280 + 64 + 2048 + 2048) * 4;
  hipMemsetAsync(degi, 0, zero_bytes, stream);

  k_convin<<<NN / 8, 256, 0, stream>>>(X, P0, W_in, b_in);
  k_deg<<<(EE + 255) / 256, 256, 0, stream>>>(dstp, degi);
  k_dinv<<<(NN + 255) / 256, 256, 0, stream>>>(degi, dinv);
  k_scan<<<1, 1024, 0, stream>>>(degi, rowptr, cursor);
  k_fill<<<(EE + 255) / 256, 256, 0, stream>>>(srcp, dstp, dinv, cursor, eidx, enrm);

  for (int l = 0; l < 2; ++l) {
    const float* g1Wl = g1_W + l * 9216;
    const float* g1bl = g1_b + l * 96;
    const float* g2Wl = g2_W + l * 9216;
    const float* g2bl = g2_b + l * 96;
    float* st = stats + l * 640;

    // gated conv 1 (bf16 input, no fold) + bn0 stats
    k_gated<1><<<NN / 8, 256, 0, stream>>>(P0, P1, g1Wl, g1bl,
                                           (const float*)nullptr, (const float*)nullptr,
                                           st + 0, st + 32);
    k_bnfin<<<1, 256, 0, stream>>>(st + 0, st + 32, bn0_g + l * 32, bn0_b + l * 32,
                                   1.0f / 400000.0f, 256, 1, AFF, BFF);
    // GEMM with bn0 fold on A-load; in-place bf16
    k_gemm<<<(NN + 63) / 64, 256, 0, stream>>>(P1, gcn_W + l * 65536, AFF, BFF);
    // GCN aggregation: CSR gather (self-loop included)
    k_gather<<<(NN + 3) / 4, 256, 0, stream>>>(P1, P2, rowptr, eidx, enrm, dinv);
    // bn1 stats + fold (gcn bias cancels in bn1)
    k_colstats<<<512, 256, 0, stream>>>(P2, NN, st + 64, st + 320);
    k_bnfin<<<1, 256, 0, stream>>>(st + 64, st + 320, bn1_g + l * 256, bn1_b + l * 256,
                                   1.0f / (float)NN, 256, 0, AFF, BFF);
    // gated conv 2 (fp32 input, bn1 fold) + bn2 stats
    k_gated<0><<<NN / 8, 256, 0, stream>>>(P2, P1, g2Wl, g2bl, AFF, BFF, st + 576, st + 608);
    k_bnfin<<<1, 256, 0, stream>>>(st + 576, st + 608, bn2_g + l * 32, bn2_b + l * 32,
                                   1.0f / 400000.0f, 32, 0, A2v, B2v);
    // finalize: bn2 + residual(x) + (relu in-place | t=7 slice)
    k_final<<<NN / 8, 256, 0, stream>>>(P0, P1, res_W + l * 1024, res_b + l * 32,
                                        A2v, B2v, xl, (l == 0) ? 0 : 1);
  }

  k_pool<<<NN * 32 / 256, 256, 0, stream>>>(xl, graphs, cnt, sp, mxu);
  k_head<<<64, 128, 0, stream>>>(cnt, sp, mxu, out_W1, out_b1, out_W2, out_b2,
                                 out_W3, out_b3, outp);

  (void)in_sizes; (void)n_in; (void)out_size; (void)ws_size;
}

// Round 4
// 1704.239 us; speedup vs baseline: 2.4933x; 1.1952x over previous
//
#include <hip/hip_runtime.h>
#include <hip/hip_bf16.h>

#define NN 50000
#define EE 400000
#define EPSF 1e-5f
#define NB 196   // (NN+255)/256

typedef unsigned short u16;
__device__ __forceinline__ float b2f(u16 u) { return __uint_as_float(((unsigned)u) << 16); }
__device__ __forceinline__ u16 f2b(float f) {
  unsigned x = __float_as_uint(f);
  unsigned r = x + 0x7FFFu + ((x >> 16) & 1u);   // RNE
  return (u16)(r >> 16);
}
__device__ __forceinline__ unsigned pack2(float lo, float hi) {
  return (unsigned)f2b(lo) | ((unsigned)f2b(hi) << 16);
}

// ---------------------------------------------------------------- conv_in
__global__ __launch_bounds__(256) void k_convin(
    const float* __restrict__ X, u16* __restrict__ out,
    const float* __restrict__ Wi, const float* __restrict__ bi)
{
  __shared__ float xs[1024];      // 8 nodes x 128
  __shared__ float wi[16 * 33];   // [ci][co] padded
  const int tid = threadIdx.x;
  for (int idx = tid; idx < 512; idx += 256) {
    int co = idx >> 4, ci = idx & 15;
    wi[ci * 33 + co] = Wi[idx];
  }
  const long xbase = (long)blockIdx.x * 1024;
  ((float4*)xs)[tid] = ((const float4*)(X + xbase))[tid];
  __syncthreads();
  const int nl = tid >> 5, c = tid & 31;
  float acc[8];
  {
    float bc = bi[c];
#pragma unroll
    for (int t = 0; t < 8; ++t) acc[t] = bc;
  }
  const float* xrow = xs + (nl << 7);
  for (int ci = 0; ci < 16; ++ci) {
    float w = wi[ci * 33 + c];
    float4 xa = *(const float4*)(xrow + ci * 8);
    float4 xb = *(const float4*)(xrow + ci * 8 + 4);
    acc[0] += xa.x * w; acc[1] += xa.y * w; acc[2] += xa.z * w; acc[3] += xa.w * w;
    acc[4] += xb.x * w; acc[5] += xb.y * w; acc[6] += xb.z * w; acc[7] += xb.w * w;
  }
  uint4 o;
  o.x = pack2(acc[0], acc[1]); o.y = pack2(acc[2], acc[3]);
  o.z = pack2(acc[4], acc[5]); o.w = pack2(acc[6], acc[7]);
  *(uint4*)(out + (long)blockIdx.x * 2048 + tid * 8) = o;
}

// ---------------------------------------------------------------- degree / dinv
__global__ void k_deg(const int* __restrict__ dst, int* __restrict__ degi)
{
  int e = blockIdx.x * 256 + threadIdx.x;
  if (e < EE) atomicAdd(degi + dst[e], 1);
}
__global__ void k_dinv(const int* __restrict__ degi, float* __restrict__ dinv)
{
  int n = blockIdx.x * 256 + threadIdx.x;
  if (n < NN) dinv[n] = rsqrtf((float)degi[n] + 1.0f);
}

// ---------------------------------------------------------------- CSR build (3-phase scan)
__global__ __launch_bounds__(256) void k_psum(const int* __restrict__ degi,
                                              int* __restrict__ bsum)
{
  __shared__ int red[4];
  const int tid = threadIdx.x;
  int i = blockIdx.x * 256 + tid;
  int v = (i < NN) ? degi[i] : 0;
#pragma unroll
  for (int d = 32; d >= 1; d >>= 1) v += __shfl_down(v, d);
  if ((tid & 63) == 0) red[tid >> 6] = v;
  __syncthreads();
  if (tid == 0) bsum[blockIdx.x] = red[0] + red[1] + red[2] + red[3];
}

__global__ __launch_bounds__(256) void k_bscan(const int* __restrict__ bsum,
                                               int* __restrict__ boff)
{
  __shared__ int wsum[4];
  const int tid = threadIdx.x, lane = tid & 63, wv = tid >> 6;
  int v = (tid < NB) ? bsum[tid] : 0;
  int s = v;
#pragma unroll
  for (int d = 1; d < 64; d <<= 1) { int t = __shfl_up(s, d); if (lane >= d) s += t; }
  if (lane == 63) wsum[wv] = s;
  __syncthreads();
  int wo = 0;
  for (int w = 0; w < wv; ++w) wo += wsum[w];
  if (tid < NB) boff[tid] = wo + s - v;
}

__global__ __launch_bounds__(256) void k_scan2(const int* __restrict__ degi,
                                               const int* __restrict__ boff,
                                               int* __restrict__ rowptr,
                                               int* __restrict__ cursor)
{
  __shared__ int wsum[4];
  const int tid = threadIdx.x, lane = tid & 63, wv = tid >> 6;
  int i = blockIdx.x * 256 + tid;
  int v = (i < NN) ? degi[i] : 0;
  int s = v;
#pragma unroll
  for (int d = 1; d < 64; d <<= 1) { int t = __shfl_up(s, d); if (lane >= d) s += t; }
  if (lane == 63) wsum[wv] = s;
  __syncthreads();
  int wo = 0;
  for (int w = 0; w < wv; ++w) wo += wsum[w];
  int excl = boff[blockIdx.x] + wo + (s - v);
  if (i < NN) { rowptr[i] = excl; cursor[i] = excl; }
  if (i == NN) rowptr[NN] = excl;   // total (v=0 padding beyond NN)
}

__global__ void k_fill(const int* __restrict__ src, const int* __restrict__ dst,
                       const float* __restrict__ dinv,
                       int* __restrict__ cursor,
                       int* __restrict__ eidx, float* __restrict__ enrm)
{
  int e = blockIdx.x * 256 + threadIdx.x;
  if (e < EE) {
    int s = src[e], d = dst[e];
    int p = atomicAdd(cursor + d, 1);
    eidx[p] = s;
    enrm[p] = dinv[s] * dinv[d];
  }
}

// ---------------------------------------------------------------- GCN gather
__global__ __launch_bounds__(256) void k_gather(
    const u16* __restrict__ hw, float* __restrict__ out,
    const int* __restrict__ rowptr, const int* __restrict__ eidx,
    const float* __restrict__ enrm, const float* __restrict__ dinv)
{
  const int wid = (blockIdx.x << 2) + (threadIdx.x >> 6);
  if (wid >= NN) return;
  const int lane = threadIdx.x & 63;
  const int c0 = lane << 2;
  float a0, a1, a2, a3;
  {
    float d2 = dinv[wid]; d2 *= d2;
    uint2 v = *(const uint2*)(hw + (long)wid * 256 + c0);
    a0 = d2 * b2f((u16)(v.x & 0xFFFF)); a1 = d2 * b2f((u16)(v.x >> 16));
    a2 = d2 * b2f((u16)(v.y & 0xFFFF)); a3 = d2 * b2f((u16)(v.y >> 16));
  }
  int p = rowptr[wid];
  const int end = rowptr[wid + 1];
  for (; p + 1 < end; p += 2) {
    int s0 = eidx[p], s1 = eidx[p + 1];
    float n0 = enrm[p], n1 = enrm[p + 1];
    uint2 v0 = *(const uint2*)(hw + (long)s0 * 256 + c0);
    uint2 v1 = *(const uint2*)(hw + (long)s1 * 256 + c0);
    a0 += n0 * b2f((u16)(v0.x & 0xFFFF)) + n1 * b2f((u16)(v1.x & 0xFFFF));
    a1 += n0 * b2f((u16)(v0.x >> 16))    + n1 * b2f((u16)(v1.x >> 16));
    a2 += n0 * b2f((u16)(v0.y & 0xFFFF)) + n1 * b2f((u16)(v1.y & 0xFFFF));
    a3 += n0 * b2f((u16)(v0.y >> 16))    + n1 * b2f((u16)(v1.y >> 16));
  }
  if (p < end) {
    int s0 = eidx[p];
    float n0 = enrm[p];
    uint2 v0 = *(const uint2*)(hw + (long)s0 * 256 + c0);
    a0 += n0 * b2f((u16)(v0.x & 0xFFFF));
    a1 += n0 * b2f((u16)(v0.x >> 16));
    a2 += n0 * b2f((u16)(v0.y & 0xFFFF));
    a3 += n0 * b2f((u16)(v0.y >> 16));
  }
  *(float4*)(out + (long)wid * 256 + c0) = make_float4(a0, a1, a2, a3);
}

// ---------------------------------------------------------------- gated conv
#define CONV_STEP(ACC, W0, W1, W2)                    \
  ACC[0] += xv[0]*W1 + xv[1]*W2;                      \
  ACC[1] += xv[0]*W0 + xv[1]*W1 + xv[2]*W2;           \
  ACC[2] += xv[1]*W0 + xv[2]*W1 + xv[3]*W2;           \
  ACC[3] += xv[2]*W0 + xv[3]*W1 + xv[4]*W2;           \
  ACC[4] += xv[3]*W0 + xv[4]*W1 + xv[5]*W2;           \
  ACC[5] += xv[4]*W0 + xv[5]*W1 + xv[6]*W2;           \
  ACC[6] += xv[5]*W0 + xv[6]*W1 + xv[7]*W2;           \
  ACC[7] += xv[6]*W0 + xv[7]*W1;

template<int INBF>
__global__ __launch_bounds__(256) void k_gated(
    const void* __restrict__ in_, u16* __restrict__ out,
    const float* __restrict__ Wg,   // (3,32,32,3)
    const float* __restrict__ bg,   // (3,32)
    const float* __restrict__ aff, const float* __restrict__ bff, // per-f (256) or null
    float* __restrict__ s1, float* __restrict__ s2)               // [32]
{
  __shared__ float xs[2048];
  __shared__ float wl[3 * 96 * 33];
  __shared__ float red1[128], red2[128];
  const int tid = threadIdx.x;

  for (int idx = tid; idx < 9216; idx += 256) {
    int conv = idx / 3072;
    int r = idx - conv * 3072;
    int co = r / 96;
    int r2 = r - co * 96;                 // ci*3+dt
    wl[conv * 3168 + r2 * 33 + co] = Wg[idx];
  }
  const long base = (long)blockIdx.x * 2048;
  if (INBF) {
    const uint4 v = *((const uint4*)((const u16*)in_ + base) + tid);
    float* d = xs + tid * 8;
    d[0] = b2f((u16)(v.x & 0xFFFF)); d[1] = b2f((u16)(v.x >> 16));
    d[2] = b2f((u16)(v.y & 0xFFFF)); d[3] = b2f((u16)(v.y >> 16));
    d[4] = b2f((u16)(v.z & 0xFFFF)); d[5] = b2f((u16)(v.z >> 16));
    d[6] = b2f((u16)(v.w & 0xFFFF)); d[7] = b2f((u16)(v.w >> 16));
  } else {
    const float* in = (const float*)in_;
#pragma unroll
    for (int i = 0; i < 2; ++i) {
      int idx = tid + (i << 8);
      float4 v = ((const float4*)(in + base))[idx];
      int f = (idx & 63) << 2;
      float4 a4 = *(const float4*)(aff + f);
      float4 b4 = *(const float4*)(bff + f);
      v.x = fmaf(a4.x, v.x, b4.x);
      v.y = fmaf(a4.y, v.y, b4.y);
      v.z = fmaf(a4.z, v.z, b4.z);
      v.w = fmaf(a4.w, v.w, b4.w);
      ((float4*)xs)[idx] = v;
    }
  }
  __syncthreads();

  const int nl = tid >> 5, c = tid & 31;
  float accP[8], accQ[8], accR[8];
  {
    float bP = bg[c], bQ = bg[32 + c], bR = bg[64 + c];
#pragma unroll
    for (int t = 0; t < 8; ++t) { accP[t] = bP; accQ[t] = bQ; accR[t] = bR; }
  }
  const float* xrow = xs + (nl << 8);
  for (int ci = 0; ci < 32; ++ci) {
    float4 xa = *(const float4*)(xrow + ci * 8);
    float4 xb = *(const float4*)(xrow + ci * 8 + 4);
    float xv[8] = {xa.x, xa.y, xa.z, xa.w, xb.x, xb.y, xb.z, xb.w};
    const float* wb0 = wl + ci * 99 + c;
    {
      float w0 = wb0[0], w1 = wb0[33], w2 = wb0[66];
      CONV_STEP(accP, w0, w1, w2)
    }
    {
      const float* wb = wb0 + 3168;
      float w0 = wb[0], w1 = wb[33], w2 = wb[66];
      CONV_STEP(accQ, w0, w1, w2)
    }
    {
      const float* wb = wb0 + 6336;
      float w0 = wb[0], w1 = wb[33], w2 = wb[66];
      CONV_STEP(accR, w0, w1, w2)
    }
  }
  float hv[8];
  float hsum = 0.0f, hsq = 0.0f;
#pragma unroll
  for (int t = 0; t < 8; ++t) {
    float q = 1.0f / (1.0f + expf(-accQ[t]));
    float h = fmaxf(accP[t] * q + accR[t], 0.0f);
    hv[t] = h; hsum += h; hsq += h * h;
  }
  {
    uint4 o;
    o.x = pack2(hv[0], hv[1]); o.y = pack2(hv[2], hv[3]);
    o.z = pack2(hv[4], hv[5]); o.w = pack2(hv[6], hv[7]);
    *(uint4*)(out + base + tid * 8) = o;
  }
  float o1 = hsum + __shfl_down(hsum, 32);
  float o2 = hsq + __shfl_down(hsq, 32);
  int wave = tid >> 6, lane = tid & 63;
  if (lane < 32) { red1[wave * 32 + lane] = o1; red2[wave * 32 + lane] = o2; }
  __syncthreads();
  if (tid < 32) {
    float a = red1[tid] + red1[32 + tid] + red1[64 + tid] + red1[96 + tid];
    float b = red2[tid] + red2[32 + tid] + red2[64 + tid] + red2[96 + tid];
    atomicAdd(s1 + tid, a);
    atomicAdd(s2 + tid, b);
  }
}

// ---------------------------------------------------------------- bn finalize
__global__ void k_bnfin(const float* __restrict__ s1, const float* __restrict__ s2,
                        const float* __restrict__ g, const float* __restrict__ b,
                        float cntInv, int nf, int expand,
                        float* __restrict__ A, float* __restrict__ B)
{
  int f = threadIdx.x;
  if (f < nf) {
    int c = expand ? (f >> 3) : f;
    float m = s1[c] * cntInv;
    float var = s2[c] * cntInv - m * m;
    float a = g[c] / sqrtf(var + EPSF);
    A[f] = a;
    B[f] = b[c] - m * a;
  }
}

// ---------------------------------------------------------------- GEMM (in-place, bf16)
__global__ __launch_bounds__(256) void k_gemm(
    u16* __restrict__ A, const float* __restrict__ W,
    const float* __restrict__ aff, const float* __restrict__ bff)
{
  __shared__ float a_lds[32 * 65];
  __shared__ float b_lds[32 * 256];
  const int tid = threadIdx.x;
  const int n0 = blockIdx.x * 64;
  const int rg = tid >> 5;   // 0..7 -> rows rg*8..+7
  const int cg = tid & 31;   // cols cg*4..+3 and 128+cg*4..+3
  float acc[8][8];
#pragma unroll
  for (int i = 0; i < 8; ++i)
#pragma unroll
    for (int j = 0; j < 8; ++j) acc[i][j] = 0.0f;

  for (int k0 = 0; k0 < 256; k0 += 32) {
    if (k0) __syncthreads();
    {
      int r = tid >> 2;               // 0..63
      int cc = (tid & 3) << 3;        // 0,8,16,24
      int n = n0 + r;
      float xv[8];
      if (n < NN) {
        uint4 v = *(const uint4*)(A + (long)n * 256 + k0 + cc);
        xv[0] = b2f((u16)(v.x & 0xFFFF)); xv[1] = b2f((u16)(v.x >> 16));
        xv[2] = b2f((u16)(v.y & 0xFFFF)); xv[3] = b2f((u16)(v.y >> 16));
        xv[4] = b2f((u16)(v.z & 0xFFFF)); xv[5] = b2f((u16)(v.z >> 16));
        xv[6] = b2f((u16)(v.w & 0xFFFF)); xv[7] = b2f((u16)(v.w >> 16));
      } else {
#pragma unroll
        for (int j = 0; j < 8; ++j) xv[j] = 0.0f;
      }
#pragma unroll
      for (int j = 0; j < 8; ++j) {
        a_lds[(cc + j) * 65 + r] = fmaf(aff[k0 + cc + j], xv[j], bff[k0 + cc + j]);
      }
    }
#pragma unroll
    for (int i = 0; i < 8; ++i) {
      int fid = (i << 8) + tid;        // float4 units, 0..2047
      int r = fid >> 6;
      int c4 = fid & 63;
      float4 v = *(const float4*)(W + (long)(k0 + r) * 256 + (c4 << 2));
      *(float4*)(b_lds + (r << 8) + (c4 << 2)) = v;
    }
    __syncthreads();
#pragma unroll
    for (int k = 0; k < 32; ++k) {
      const float* ap = a_lds + k * 65 + (rg << 3);
      const float* bp = b_lds + (k << 8) + (cg << 2);
      float4 a0 = *(const float4*)ap;
      float4 a1 = *(const float4*)(ap + 4);
      float4 b0 = *(const float4*)bp;
      float4 b1 = *(const float4*)(bp + 128);
      float av[8] = {a0.x, a0.y, a0.z, a0.w, a1.x, a1.y, a1.z, a1.w};
      float bv[8] = {b0.x, b0.y, b0.z, b0.w, b1.x, b1.y, b1.z, b1.w};
#pragma unroll
      for (int i = 0; i < 8; ++i)
#pragma unroll
        for (int j = 0; j < 8; ++j) acc[i][j] += av[i] * bv[j];
    }
  }
#pragma unroll
  for (int i = 0; i < 8; ++i) {
    int n = n0 + (rg << 3) + i;
    if (n < NN) {
      long rb = (long)n * 256 + (cg << 2);
      uint2 s0, s1v;
      s0.x = pack2(acc[i][0], acc[i][1]); s0.y = pack2(acc[i][2], acc[i][3]);
      s1v.x = pack2(acc[i][4], acc[i][5]); s1v.y = pack2(acc[i][6], acc[i][7]);
      *(uint2*)(A + rb) = s0;
      *(uint2*)(A + rb + 128) = s1v;
    }
  }
}

// ---------------------------------------------------------------- per-feature col stats
__global__ void k_colstats(const float* __restrict__ x, int rows,
                           float* __restrict__ s1, float* __restrict__ s2)
{
  int f = threadIdx.x;   // 256
  float a = 0.0f, b = 0.0f;
  for (int n = blockIdx.x; n < rows; n += gridDim.x) {
    float v = x[(long)n * 256 + f];
    a += v; b += v * v;
  }
  atomicAdd(s1 + f, a);
  atomicAdd(s2 + f, b);
}

// ---------------------------------------------------------------- finalize layer
__global__ __launch_bounds__(256) void k_final(
    u16* __restrict__ x, const u16* __restrict__ h2,
    const float* __restrict__ resW, const float* __restrict__ resb,
    const float* __restrict__ A2, const float* __restrict__ B2,
    float* __restrict__ xl, int mode)
{
  __shared__ float xs[2048];
  __shared__ float wr[32 * 33];
  const int tid = threadIdx.x;
  for (int idx = tid; idx < 1024; idx += 256) {
    int co = idx >> 5, ci = idx & 31;
    wr[ci * 33 + co] = resW[idx];
  }
  const long base = (long)blockIdx.x * 2048;
  {
    const uint4 v = *((const uint4*)(x + base) + tid);
    float* d = xs + tid * 8;
    d[0] = b2f((u16)(v.x & 0xFFFF)); d[1] = b2f((u16)(v.x >> 16));
    d[2] = b2f((u16)(v.y & 0xFFFF)); d[3] = b2f((u16)(v.y >> 16));
    d[4] = b2f((u16)(v.z & 0xFFFF)); d[5] = b2f((u16)(v.z >> 16));
    d[6] = b2f((u16)(v.w & 0xFFFF)); d[7] = b2f((u16)(v.w >> 16));
  }
  __syncthreads();
  const int nl = tid >> 5, c = tid & 31;
  float r[8];
  {
    float rb = resb[c];
#pragma unroll
    for (int t = 0; t < 8; ++t) r[t] = rb;
  }
  const float* xrow = xs + (nl << 8);
  for (int ci = 0; ci < 32; ++ci) {
    float w = wr[ci * 33 + c];
    float4 xa = *(const float4*)(xrow + ci * 8);
    float4 xb = *(const float4*)(xrow + ci * 8 + 4);
    r[0] += xa.x * w; r[1] += xa.y * w; r[2] += xa.z * w; r[3] += xa.w * w;
    r[4] += xb.x * w; r[5] += xb.y * w; r[6] += xb.z * w; r[7] += xb.w * w;
  }
  float a2 = A2[c], b2 = B2[c];
  float hv[8];
  {
    const uint4 v = *((const uint4*)(h2 + base) + tid);
    hv[0] = b2f((u16)(v.x & 0xFFFF)); hv[1] = b2f((u16)(v.x >> 16));
    hv[2] = b2f((u16)(v.y & 0xFFFF)); hv[3] = b2f((u16)(v.y >> 16));
    hv[4] = b2f((u16)(v.z & 0xFFFF)); hv[5] = b2f((u16)(v.z >> 16));
    hv[6] = b2f((u16)(v.w & 0xFFFF)); hv[7] = b2f((u16)(v.w >> 16));
  }
  if (mode == 0) {
    uint4 o;
    float ov[8];
#pragma unroll
    for (int t = 0; t < 8; ++t) ov[t] = fmaxf(fmaf(a2, hv[t], b2) + r[t], 0.0f);
    o.x = pack2(ov[0], ov[1]); o.y = pack2(ov[2], ov[3]);
    o.z = pack2(ov[4], ov[5]); o.w = pack2(ov[6], ov[7]);
    *(uint4*)(x + base + tid * 8) = o;
  } else {
    float v = fmaf(a2, hv[7], b2) + r[7];
    int n = blockIdx.x * 8 + nl;
    xl[n * 32 + c] = v;
  }
}

// ---------------------------------------------------------------- pooling (sorted graphs)
// block = 256 contiguous nodes; per-thread run-accumulate, LDS combine, few global atomics
__global__ __launch_bounds__(256) void k_pool(
    const float* __restrict__ xl, const int* __restrict__ graphs,
    int* __restrict__ cnt, float* __restrict__ sp, unsigned* __restrict__ mxu)
{
  __shared__ float lsum[64 * 32];
  __shared__ unsigned lmax[64 * 32];
  __shared__ int lcnt[64];
  const int tid = threadIdx.x;
  const int n0 = blockIdx.x << 8;
  const int nend = min(n0 + 256, NN);
  const int gmin = graphs[n0];
  const int gmax = graphs[nend - 1];
  const int span = gmax - gmin + 1;          // <= 64
  for (int i = tid; i < span * 32; i += 256) { lsum[i] = 0.0f; lmax[i] = 0u; }
  for (int i = tid; i < span; i += 256) lcnt[i] = 0;
  __syncthreads();
  const int c = tid & 31;
  const int nbase = n0 + ((tid >> 5) << 5);
  int curg = -1; float s = 0.0f; unsigned m = 0u; int cn = 0;
  for (int i = 0; i < 32; ++i) {
    int n = nbase + i;
    if (n >= nend) break;
    int g = graphs[n];
    float v = xl[(n << 5) + c];
    unsigned u = __float_as_uint(v);
    u = (u & 0x80000000u) ? ~u : (u | 0x80000000u);
    if (g != curg) {
      if (curg >= 0) {
        atomicAdd(&lsum[((curg - gmin) << 5) + c], s);
        atomicMax(&lmax[((curg - gmin) << 5) + c], m);
        if (c == 0) atomicAdd(&lcnt[curg - gmin], cn);
      }
      curg = g; s = v; m = u; cn = 1;
    } else {
      s += v; m = (u > m) ? u : m; cn++;
    }
  }
  if (curg >= 0) {
    atomicAdd(&lsum[((curg - gmin) << 5) + c], s);
    atomicMax(&lmax[((curg - gmin) << 5) + c], m);
    if (c == 0) atomicAdd(&lcnt[curg - gmin], cn);
  }
  __syncthreads();
  for (int i = tid; i < span * 32; i += 256) {
    atomicAdd(sp + (gmin << 5) + i, lsum[i]);
    atomicMax(mxu + (gmin << 5) + i, lmax[i]);
  }
  for (int i = tid; i < span; i += 256)
    if (lcnt[i]) atomicAdd(cnt + gmin + i, lcnt[i]);
}

// ---------------------------------------------------------------- MLP head
__global__ __launch_bounds__(128) void k_head(
    const int* __restrict__ cnt, const float* __restrict__ sp,
    const unsigned* __restrict__ mxu,
    const float* __restrict__ W1, const float* __restrict__ b1,
    const float* __restrict__ W2, const float* __restrict__ b2,
    const float* __restrict__ W3, const float* __restrict__ b3,
    float* __restrict__ out)
{
  __shared__ float xg[96], hh1[128], hh2[64];
  const int g = blockIdx.x, tid = threadIdx.x;
  if (tid < 32) {
    float s = sp[g * 32 + tid];
    int cn = cnt[g];
    float mean = s / fmaxf((float)cn, 1.0f);
    float mx = 0.0f;
    if (cn > 0) {
      unsigned u = mxu[g * 32 + tid];
      unsigned ub = (u & 0x80000000u) ? (u ^ 0x80000000u) : ~u;
      mx = __uint_as_float(ub);
    }
    xg[tid] = mean; xg[32 + tid] = mx; xg[64 + tid] = s;
  }
  __syncthreads();
  {
    float a = b1[tid];
    for (int k = 0; k < 96; ++k) a += xg[k] * W1[k * 128 + tid];
    hh1[tid] = fmaxf(a, 0.0f);
  }
  __syncthreads();
  if (tid < 64) {
    float a = b2[tid];
    for (int k = 0; k < 128; ++k) a += hh1[k] * W2[k * 64 + tid];
    hh2[tid] = fmaxf(a, 0.0f);
  }
  __syncthreads();
  if (tid < 64) {
    float p = hh2[tid] * W3[tid];
    for (int off = 32; off; off >>= 1) p += __shfl_down(p, off);
    if (tid == 0) out[g] = p + b3[0];
  }
}

// ================================================================ launch
extern "C" void kernel_launch(void* const* d_in, const int* in_sizes, int n_in,
                              void* d_out, int out_size, void* d_ws, size_t ws_size,
                              hipStream_t stream)
{
  const float* X       = (const float*)d_in[0];
  const int*   edge    = (const int*)d_in[1];
  const int*   graphs  = (const int*)d_in[2];
  const float* W_in    = (const float*)d_in[3];
  const float* b_in    = (const float*)d_in[4];
  const float* res_W   = (const float*)d_in[5];
  const float* res_b   = (const float*)d_in[6];
  const float* g1_W    = (const float*)d_in[7];
  const float* g1_b    = (const float*)d_in[8];
  const float* bn0_g   = (const float*)d_in[9];
  const float* bn0_b   = (const float*)d_in[10];
  const float* gcn_W   = (const float*)d_in[11];
  // d_in[12] = gcn_b: cancels in bn1 (per-feature shift removed by mean over axis 0)
  const float* bn1_g   = (const float*)d_in[13];
  const float* bn1_b   = (const float*)d_in[14];
  const float* g2_W    = (const float*)d_in[15];
  const float* g2_b    = (const float*)d_in[16];
  const float* bn2_g   = (const float*)d_in[17];
  const float* bn2_b   = (const float*)d_in[18];
  const float* out_W1  = (const float*)d_in[19];
  const float* out_b1  = (const float*)d_in[20];
  const float* out_W2  = (const float*)d_in[21];
  const float* out_b2  = (const float*)d_in[22];
  const float* out_W3  = (const float*)d_in[23];
  const float* out_b3  = (const float*)d_in[24];
  float* outp = (float*)d_out;

  const int* srcp = edge;
  const int* dstp = edge + EE;

  // ---- workspace layout (~113 MB) ----
  const long BIGE = (long)NN * 256;              // 12.8M elems
  u16*   P0   = (u16*)d_ws;                      // x, bf16      25.6 MB
  u16*   P1   = P0 + BIGE;                       // h1/hw, bf16  25.6 MB
  float* P2   = (float*)(P1 + BIGE);             // g, fp32      51.2 MB
  float* xl   = P2 + BIGE;                       // N*32 fp32     6.4 MB
  float* dinv = xl + (long)NN * 32;              // N
  int*   rowptr = (int*)(dinv + NN);             // N+1
  int*   cursor = rowptr + NN + 1;               // N
  int*   eidx   = cursor + NN;                   // E
  float* enrm   = (float*)(eidx + EE);           // E
  int*   bsum   = (int*)(enrm + EE);             // NB
  int*   boff   = bsum + NB;                     // NB
  int*   degi = boff + NB;                       // N      <- zero region start
  float* stats = (float*)(degi + NN);            // 1280 (2 layers x 640)
  int*   cnt  = (int*)(stats + 1280);            // 64
  float* sp   = stats + 1280 + 64;               // 2048
  unsigned* mxu = (unsigned*)(sp + 2048);        // 2048   <- zero region end
  float* AFF  = sp + 2048 + 2048;                // 256
  float* BFF  = AFF + 256;
  float* A2v  = BFF + 256;
  float* B2v  = A2v + 32;

  const size_t zero_bytes = (size_t)(NN + 1280 + 64 + 2048 + 2048) * 4;
  hipMemsetAsync(degi, 0, zero_bytes, stream);

  k_convin<<<NN / 8, 256, 0, stream>>>(X, P0, W_in, b_in);
  k_deg<<<(EE + 255) / 256, 256, 0, stream>>>(dstp, degi);
  k_dinv<<<(NN + 255) / 256, 256, 0, stream>>>(degi, dinv);
  k_psum<<<NB, 256, 0, stream>>>(degi, bsum);
  k_bscan<<<1, 256, 0, stream>>>(bsum, boff);
  k_scan2<<<NB, 256, 0, stream>>>(degi, boff, rowptr, cursor);
  k_fill<<<(EE + 255) / 256, 256, 0, stream>>>(srcp, dstp, dinv, cursor, eidx, enrm);

  for (int l = 0; l < 2; ++l) {
    const float* g1Wl = g1_W + l * 9216;
    const float* g1bl = g1_b + l * 96;
    const float* g2Wl = g2_W + l * 9216;
    const float* g2bl = g2_b + l * 96;
    float* st = stats + l * 640;

    // gated conv 1 (bf16 input, no fold) + bn0 stats
    k_gated<1><<<NN / 8, 256, 0, stream>>>(P0, P1, g1Wl, g1bl,
                                           (const float*)nullptr, (const float*)nullptr,
                                           st + 0, st + 32);
    k_bnfin<<<1, 256, 0, stream>>>(st + 0, st + 32, bn0_g + l * 32, bn0_b + l * 32,
                                   1.0f / 400000.0f, 256, 1, AFF, BFF);
    // GEMM with bn0 fold on A-load; in-place bf16
    k_gemm<<<(NN + 63) / 64, 256, 0, stream>>>(P1, gcn_W + l * 65536, AFF, BFF);
    // GCN aggregation: CSR gather (self-loop included)
    k_gather<<<(NN + 3) / 4, 256, 0, stream>>>(P1, P2, rowptr, eidx, enrm, dinv);
    // bn1 stats + fold (gcn bias cancels in bn1)
    k_colstats<<<512, 256, 0, stream>>>(P2, NN, st + 64, st + 320);
    k_bnfin<<<1, 256, 0, stream>>>(st + 64, st + 320, bn1_g + l * 256, bn1_b + l * 256,
                                   1.0f / (float)NN, 256, 0, AFF, BFF);
    // gated conv 2 (fp32 input, bn1 fold) + bn2 stats
    k_gated<0><<<NN / 8, 256, 0, stream>>>(P2, P1, g2Wl, g2bl, AFF, BFF, st + 576, st + 608);
    k_bnfin<<<1, 256, 0, stream>>>(st + 576, st + 608, bn2_g + l * 32, bn2_b + l * 32,
                                   1.0f / 400000.0f, 32, 0, A2v, B2v);
    // finalize: bn2 + residual(x) + (relu in-place | t=7 slice)
    k_final<<<NN / 8, 256, 0, stream>>>(P0, P1, res_W + l * 1024, res_b + l * 32,
                                        A2v, B2v, xl, (l == 0) ? 0 : 1);
  }

  k_pool<<<(NN + 255) / 256, 256, 0, stream>>>(xl, graphs, cnt, sp, mxu);
  k_head<<<64, 128, 0, stream>>>(cnt, sp, mxu, out_W1, out_b1, out_W2, out_b2,
                                 out_W3, out_b3, outp);

  (void)in_sizes; (void)n_in; (void)out_size; (void)ws_size;
}